// Round 11
// baseline (3750.013 us; speedup 1.0000x reference)
//
#include <hip/hip_runtime.h>
#include <hip/hip_fp16.h>

// RNN h_{t+1} = tanh(x_t*W_ih + b_ih + b_hh + h_t @ W_hh^T), T=1024, B=64, H=512.
//
// Round 11: single CU per batch, 64 WGs x 256 thr, __launch_bounds__(256,1).
// Ledger: cross-CU exchange L >= ~1900cy/step (R2/R10); 512-thr WGs cap at 128
// arch VGPRs (R3/6/7/8); 256-thr WGs DO promote plain arrays (R1:156, R2:136;
// m08: no spill through 450). So: keep everything on one CU and put 75% of the
// weights in arch VGPRs, streaming the rest on the LDS + VMEM pipes which
// overlap the 1024cy VALU floor.
//  - Thread (w=tid>>6, i=lane&15, g=lane>>4): rows j_m = 128w+16m+i (m=0..7)
//    over k-window halves [128g,128g+128) = 64 h2-uints/row.
//    Per row: uints 0..47 -> regs (8 arrays of 48 = 384 VGPRs);
//             uints 48..55 -> LDS  wl[2m..2m+1][tid]  (64KB, per-wave contiguous);
//             uints 56..63 -> ws   wsT[2m..2m+1][tid] (64KB, L2-resident,
//             self-written in prologue, self-read -> benign identical races).
//  - h fp16 in LDS, 272B window stride: one b128 broadcast read serves the 4
//    windows from 4 disjoint bank spans -> conflict-free.
//  - Reduce over 4 windows: shfl_xor(16)+shfl_xor(32); lane publishes rows
//    m=g and m=g+4 (each row exactly once). ONE __syncthreads per step.
//  - Tail loads batched <=8 uint4 in flight, issued before the reg-dot blocks
//    that hide them; zr trick (R7-verified) keeps them in-loop.

#define BB 64
#define TT 1024
#define HH 512

typedef _Float16 half2_t __attribute__((ext_vector_type(2)));

__device__ __forceinline__ float dot2f(unsigned h, unsigned w, float acc) {
    return __builtin_amdgcn_fdot2(__builtin_bit_cast(half2_t, h),
                                  __builtin_bit_cast(half2_t, w), acc, false);
}
__device__ __forceinline__ float fast_tanh(float z) {
    float e = __expf(2.0f * z);
    return fmaf(-2.0f, __builtin_amdgcn_rcpf(e + 1.0f), 1.0f);
}
__device__ __forceinline__ unsigned pack_h2(float a, float b) {
    return __builtin_bit_cast(unsigned, __floats2half2_rn(a, b));
}

#define DOT4(U, WV, A) { A = dot2f((U).x,(WV).x,A); A = dot2f((U).y,(WV).y,A); \
                         A = dot2f((U).z,(WV).z,A); A = dot2f((U).w,(WV).w,A); }
// one h-chunk against all 8 rows' reg weights
#define DOTC(U, C) \
  a0=dot2f((U).x,w0[4*(C)],a0); a0=dot2f((U).y,w0[4*(C)+1],a0); a0=dot2f((U).z,w0[4*(C)+2],a0); a0=dot2f((U).w,w0[4*(C)+3],a0); \
  a1=dot2f((U).x,w1[4*(C)],a1); a1=dot2f((U).y,w1[4*(C)+1],a1); a1=dot2f((U).z,w1[4*(C)+2],a1); a1=dot2f((U).w,w1[4*(C)+3],a1); \
  a2=dot2f((U).x,w2[4*(C)],a2); a2=dot2f((U).y,w2[4*(C)+1],a2); a2=dot2f((U).z,w2[4*(C)+2],a2); a2=dot2f((U).w,w2[4*(C)+3],a2); \
  a3=dot2f((U).x,w3[4*(C)],a3); a3=dot2f((U).y,w3[4*(C)+1],a3); a3=dot2f((U).z,w3[4*(C)+2],a3); a3=dot2f((U).w,w3[4*(C)+3],a3); \
  a4=dot2f((U).x,w4[4*(C)],a4); a4=dot2f((U).y,w4[4*(C)+1],a4); a4=dot2f((U).z,w4[4*(C)+2],a4); a4=dot2f((U).w,w4[4*(C)+3],a4); \
  a5=dot2f((U).x,w5[4*(C)],a5); a5=dot2f((U).y,w5[4*(C)+1],a5); a5=dot2f((U).z,w5[4*(C)+2],a5); a5=dot2f((U).w,w5[4*(C)+3],a5); \
  a6=dot2f((U).x,w6[4*(C)],a6); a6=dot2f((U).y,w6[4*(C)+1],a6); a6=dot2f((U).z,w6[4*(C)+2],a6); a6=dot2f((U).w,w6[4*(C)+3],a6); \
  a7=dot2f((U).x,w7[4*(C)],a7); a7=dot2f((U).y,w7[4*(C)+1],a7); a7=dot2f((U).z,w7[4*(C)+2],a7); a7=dot2f((U).w,w7[4*(C)+3],a7);

#define PROW(M) { \
  const float4* rp = reinterpret_cast<const float4*>( \
      W_hh + (size_t)(128 * w + 16 * M + i) * HH + 128 * g); \
  _Pragma("unroll") \
  for (int d = 0; d < 24; ++d) { \
    const float4 f = rp[d]; \
    w##M[2*d] = pack_h2(f.x, f.y); w##M[2*d+1] = pack_h2(f.z, f.w); } \
  { const float4 f0=rp[24], f1=rp[25], f2=rp[26], f3=rp[27]; \
    const float4 f4=rp[28], f5=rp[29], f6=rp[30], f7=rp[31]; \
    wl[2*M][tid]   = make_uint4(pack_h2(f0.x,f0.y),pack_h2(f0.z,f0.w),pack_h2(f1.x,f1.y),pack_h2(f1.z,f1.w)); \
    wl[2*M+1][tid] = make_uint4(pack_h2(f2.x,f2.y),pack_h2(f2.z,f2.w),pack_h2(f3.x,f3.y),pack_h2(f3.z,f3.w)); \
    wsT[(2*M)*256+tid]   = make_uint4(pack_h2(f4.x,f4.y),pack_h2(f4.z,f4.w),pack_h2(f5.x,f5.y),pack_h2(f5.z,f5.w)); \
    wsT[(2*M+1)*256+tid] = make_uint4(pack_h2(f6.x,f6.y),pack_h2(f6.z,f6.w),pack_h2(f7.x,f7.y),pack_h2(f7.z,f7.w)); } }

__launch_bounds__(256, 1)
__global__ void rnn_cu4(const float* __restrict__ x,      // [B,T]
                        const float* __restrict__ W_ih,   // [H]
                        const float* __restrict__ W_hh,   // [H,H]
                        const float* __restrict__ b_ih,   // [H]
                        const float* __restrict__ b_hh,   // [H]
                        const float* __restrict__ W_out,  // [H]
                        const float* __restrict__ b_out,  // [1]
                        float* __restrict__ out,          // [64 + B*H]
                        uint4* __restrict__ wsT)          // [16][256] tails
{
    const int b    = blockIdx.x;
    const int tid  = threadIdx.x;
    const int w    = tid >> 6;
    const int lane = tid & 63;
    const int i    = lane & 15;
    const int g    = lane >> 4;       // k-window 0..3

    __shared__ float xrow[TT];                            // 4KB
    __shared__ __align__(16) unsigned char hbuf[2][1088]; // 4 windows x 272B, dbuf
    __shared__ __align__(16) uint4 wl[16][256];           // LDS tails, 64KB

    for (int s = tid; s < TT; s += 256) xrow[s] = x[b * TT + s];

    unsigned w0[48], w1[48], w2[48], w3[48], w4[48], w5[48], w6[48], w7[48];
    PROW(0) PROW(1) PROW(2) PROW(3) PROW(4) PROW(5) PROW(6) PROW(7)
    asm volatile("s_waitcnt vmcnt(0)" ::: "memory");   // ws self-reads need this

    // publish rows: jA = 128w+16g+i (m=g), jB = jA+64 (m=g+4)
    const int jA = 128 * w + 16 * g + i;
    const int jB = jA + 64;
    const float wihA = W_ih[jA], wihB = W_ih[jB];
    const float biasA = b_ih[jA] + b_hh[jA];
    const float biasB = b_ih[jB] + b_hh[jB];

    __syncthreads();   // xrow + wl visible

#pragma unroll 1
    for (int t = 0; t < TT; ++t) {
        const int par = t & 1;
        float a0=0.f,a1=0.f,a2=0.f,a3=0.f,a4=0.f,a5=0.f,a6=0.f,a7=0.f;
        if (t > 0) {
            int zr; asm volatile("v_mov_b32 %0, 0" : "=v"(zr));  // keep tails in-loop
            const uint4* wsp = wsT + tid + zr;
            const uint4* wlp = &wl[0][0] + tid + zr;
            const unsigned char* hb = &hbuf[par][0] + g * 272;
#define HU(C) (*reinterpret_cast<const uint4*>(hb + (C) * 16))
            // batch A: rows 0-3 VMEM tails in flight under reg-dots 0..5
            const uint4 TA0=wsp[0*256], TA1=wsp[1*256], TA2=wsp[2*256], TA3=wsp[3*256];
            const uint4 TA4=wsp[4*256], TA5=wsp[5*256], TA6=wsp[6*256], TA7=wsp[7*256];
            uint4 u;
            u=HU(0);  DOTC(u,0)  u=HU(1);  DOTC(u,1)  u=HU(2);  DOTC(u,2)
            u=HU(3);  DOTC(u,3)  u=HU(4);  DOTC(u,4)  u=HU(5);  DOTC(u,5)
            const uint4 uE = HU(14), uF = HU(15);
            DOT4(uE,TA0,a0) DOT4(uF,TA1,a0) DOT4(uE,TA2,a1) DOT4(uF,TA3,a1)
            DOT4(uE,TA4,a2) DOT4(uF,TA5,a2) DOT4(uE,TA6,a3) DOT4(uF,TA7,a3)
            // batch B: rows 4-7 VMEM tails under reg-dots 6..11
            const uint4 TB0=wsp[8*256],  TB1=wsp[9*256],  TB2=wsp[10*256], TB3=wsp[11*256];
            const uint4 TB4=wsp[12*256], TB5=wsp[13*256], TB6=wsp[14*256], TB7=wsp[15*256];
            u=HU(6);  DOTC(u,6)  u=HU(7);  DOTC(u,7)  u=HU(8);  DOTC(u,8)
            u=HU(9);  DOTC(u,9)  u=HU(10); DOTC(u,10) u=HU(11); DOTC(u,11)
            DOT4(uE,TB0,a4) DOT4(uF,TB1,a4) DOT4(uE,TB2,a5) DOT4(uF,TB3,a5)
            DOT4(uE,TB4,a6) DOT4(uF,TB5,a6) DOT4(uE,TB6,a7) DOT4(uF,TB7,a7)
            // LDS tails (chunks 12,13), two batches of 8
            const uint4 uC = HU(12), uD = HU(13);
            const uint4 L0=wlp[0*256], L1=wlp[1*256], L2=wlp[2*256], L3=wlp[3*256];
            const uint4 L4=wlp[4*256], L5=wlp[5*256], L6=wlp[6*256], L7=wlp[7*256];
            DOT4(uC,L0,a0) DOT4(uD,L1,a0) DOT4(uC,L2,a1) DOT4(uD,L3,a1)
            DOT4(uC,L4,a2) DOT4(uD,L5,a2) DOT4(uC,L6,a3) DOT4(uD,L7,a3)
            const uint4 L8=wlp[8*256],  L9=wlp[9*256],  LA=wlp[10*256], LB=wlp[11*256];
            const uint4 LC=wlp[12*256], LD=wlp[13*256], LE=wlp[14*256], LF=wlp[15*256];
            DOT4(uC,L8,a4) DOT4(uD,L9,a4) DOT4(uC,LA,a5) DOT4(uD,LB,a5)
            DOT4(uC,LC,a6) DOT4(uD,LD,a6) DOT4(uC,LE,a7) DOT4(uD,LF,a7)
#undef HU
        }
        // ---- reduce over the 4 k-windows (lane bits 4,5) ----
        a0 += __shfl_xor(a0,16,64); a0 += __shfl_xor(a0,32,64);
        a1 += __shfl_xor(a1,16,64); a1 += __shfl_xor(a1,32,64);
        a2 += __shfl_xor(a2,16,64); a2 += __shfl_xor(a2,32,64);
        a3 += __shfl_xor(a3,16,64); a3 += __shfl_xor(a3,32,64);
        a4 += __shfl_xor(a4,16,64); a4 += __shfl_xor(a4,32,64);
        a5 += __shfl_xor(a5,16,64); a5 += __shfl_xor(a5,32,64);
        a6 += __shfl_xor(a6,16,64); a6 += __shfl_xor(a6,32,64);
        a7 += __shfl_xor(a7,16,64); a7 += __shfl_xor(a7,32,64);
        // lane publishes rows m=g and m=g+4 (compile-time select chain)
        const float vA = (g & 2) ? ((g & 1) ? a3 : a2) : ((g & 1) ? a1 : a0);
        const float vB = (g & 2) ? ((g & 1) ? a7 : a6) : ((g & 1) ? a5 : a4);
        const float xt = xrow[t];
        const float hA = fast_tanh(fmaf(xt, wihA, vA + biasA));
        const float hB = fast_tanh(fmaf(xt, wihB, vB + biasB));
        unsigned char* hw = &hbuf[par ^ 1][w * 272 + (16 * g + i) * 2];
        *reinterpret_cast<unsigned short*>(hw) =
            __builtin_bit_cast(unsigned short, (_Float16)hA);
        *reinterpret_cast<unsigned short*>(hw + 128) =
            __builtin_bit_cast(unsigned short, (_Float16)hB);
        if (t == TT - 1) {
            out[64 + b * HH + jA] = hA;
            out[64 + b * HH + jB] = hB;
        }
        __syncthreads();   // the ONLY barrier per step
    }

    // ---- epilogue: wave 0 computes out[b] = h_last . W_out + b_out ----
    if (w == 0) {   // final h landed in parity 0
        const uint4 hv = *reinterpret_cast<const uint4*>(
            &hbuf[0][(lane >> 4) * 272 + (lane & 15) * 16]);
        const int kb = 32 * (lane >> 4) + 2 * (lane & 15);
        const float4 q0 = reinterpret_cast<const float4*>(W_out)[kb];
        const float4 q1 = reinterpret_cast<const float4*>(W_out)[kb + 1];
        float s = 0.f; __half2 p;
        p = __builtin_bit_cast(__half2, hv.x);
        s = fmaf(__low2float(p), q0.x, s); s = fmaf(__high2float(p), q0.y, s);
        p = __builtin_bit_cast(__half2, hv.y);
        s = fmaf(__low2float(p), q0.z, s); s = fmaf(__high2float(p), q0.w, s);
        p = __builtin_bit_cast(__half2, hv.z);
        s = fmaf(__low2float(p), q1.x, s); s = fmaf(__high2float(p), q1.y, s);
        p = __builtin_bit_cast(__half2, hv.w);
        s = fmaf(__low2float(p), q1.z, s); s = fmaf(__high2float(p), q1.w, s);
#pragma unroll
        for (int off = 32; off; off >>= 1) s += __shfl_down(s, off, 64);
        if (lane == 0) out[b] = s + b_out[0];
    }
}

extern "C" void kernel_launch(void* const* d_in, const int* in_sizes, int n_in,
                              void* d_out, int out_size, void* d_ws, size_t ws_size,
                              hipStream_t stream) {
    const float* x     = (const float*)d_in[0];  // inputs [B,T,1]
    // d_in[1] = state (ignored; reference uses zero initial hidden state)
    const float* W_ih  = (const float*)d_in[2];
    const float* W_hh  = (const float*)d_in[3];
    const float* b_ih  = (const float*)d_in[4];
    const float* b_hh  = (const float*)d_in[5];
    const float* W_out = (const float*)d_in[6];
    const float* b_out = (const float*)d_in[7];

    uint4* wsT = (uint4*)d_ws;  // [16][256] = 64KB packed fp16 VMEM tails
    // (every WG writes identical values in its prologue, reads only its own)

    rnn_cu4<<<dim3(BB), dim3(256), 0, stream>>>(
        x, W_ih, W_hh, b_ih, b_hh, W_out, b_out, (float*)d_out, wsT);
}

// Round 12
// 1360.207 us; speedup vs baseline: 2.7569x; 2.7569x over previous
//
#include <hip/hip_runtime.h>
#include <hip/hip_fp16.h>

// RNN h_{t+1} = tanh(x_t*W_ih + b_ih + b_hh + h_t @ W_hh^T), T=1024, B=64, H=512.
//
// Round 12 = Round 10 (partial-sum exchange, zero barriers, 1116us) with a
// PIPELINED POLLER: three 4-load rounds in flight (A/B/C rotate), so the tag
// sample period drops from one full L3 latency (~800cy) to ~latency/3. The
// compiler's waitcnt pass emits vmcnt(8) before each round's check (only that
// round waited); sched_barrier(0) pins issue-before-check order.
//
// Structure (R10, proven): 256 WGs = 64 batches x 4 k-slices; 256 thr.
//  - WG (b,q) owns k-slice [128q,128q+128) for ALL 512 j. Thread owns rows
//    j0=128wv+2lane, j1=j0+1: two 64-uint fp16 arrays (arch-VGPR resident).
//  - Publish: ONE 8B word {tag:32|fp16 pA|fp16 pB} per row-pair, straight from
//    accumulators. Consume: poll 4 words (own rows' partials from 4 WGs), sum,
//    tanh, stage dword to wave-private LDS, 16 broadcast b128 reads, 128 dot2.
//  - Parity double-buffer; tags strictly increase; memset per call.

#define BB 64
#define TT 1024
#define HH 512
#define AG __HIP_MEMORY_SCOPE_AGENT

typedef _Float16 half2_t __attribute__((ext_vector_type(2)));
typedef unsigned uint4v __attribute__((ext_vector_type(4)));

__device__ __forceinline__ float dot2f(unsigned h, unsigned w, float acc) {
    return __builtin_amdgcn_fdot2(__builtin_bit_cast(half2_t, h),
                                  __builtin_bit_cast(half2_t, w), acc, false);
}
__device__ __forceinline__ float fast_tanh(float z) {
    float e = __expf(2.0f * z);
    return fmaf(-2.0f, __builtin_amdgcn_rcpf(e + 1.0f), 1.0f);
}
__device__ __forceinline__ unsigned pack_h2(float a, float b) {
    return __builtin_bit_cast(unsigned, __floats2half2_rn(a, b));
}
__device__ __forceinline__ float lo_f(unsigned long long v) {
    return __low2float(__builtin_bit_cast(__half2, (unsigned)v));
}
__device__ __forceinline__ float hi_f(unsigned long long v) {
    return __high2float(__builtin_bit_cast(__half2, (unsigned)v));
}
__device__ __forceinline__ unsigned long long ald(const unsigned long long* p) {
    return __hip_atomic_load(p, __ATOMIC_RELAXED, AG);
}

__launch_bounds__(256, 1)
__global__ void rnn_part2(const float* __restrict__ x,      // [B,T]
                          const float* __restrict__ W_ih,   // [H]
                          const float* __restrict__ W_hh,   // [H,H]
                          const float* __restrict__ b_ih,   // [H]
                          const float* __restrict__ b_hh,   // [H]
                          const float* __restrict__ W_out,  // [H]
                          const float* __restrict__ b_out,  // [1]
                          float* __restrict__ out,          // [64 + B*H]
                          unsigned long long* __restrict__ pg) // [2][B][4][256]
{
    const int b    = blockIdx.x >> 2;   // batch
    const int q    = blockIdx.x & 3;    // k-slice of this WG
    const int tid  = threadIdx.x;
    const int wv   = tid >> 6;
    const int lane = tid & 63;

    __shared__ float xrow[TT];                 // 4KB
    __shared__ unsigned stage[4][2][64];       // per-wave h2 stage, 2KB

    for (int s = tid; s < TT; s += 256) xrow[s] = x[b * TT + s];

    // ---- publisher rows j0,j1 over k in [128q, 128q+128): 128 uints in VGPRs
    const int j0 = 128 * wv + 2 * lane;
    const int j1 = j0 + 1;
    unsigned wh0[64], wh1[64];
    {
        const float4* r0 = reinterpret_cast<const float4*>(W_hh + (size_t)j0 * HH + 128 * q);
        const float4* r1 = reinterpret_cast<const float4*>(W_hh + (size_t)j1 * HH + 128 * q);
#pragma unroll
        for (int d = 0; d < 32; ++d) {
            const float4 a = r0[d], c = r1[d];
            wh0[2 * d]     = pack_h2(a.x, a.y);
            wh0[2 * d + 1] = pack_h2(a.z, a.w);
            wh1[2 * d]     = pack_h2(c.x, c.y);
            wh1[2 * d + 1] = pack_h2(c.z, c.w);
        }
    }

    // ---- consumer rows c0,c1 = this WG's k-slice values (pair 64q+lane)
    const int c0 = 128 * q + 2 * lane;
    const int c1 = c0 + 1;
    const float wihA = W_ih[c0], wihB = W_ih[c1];
    const float bA = b_ih[c0] + b_hh[c0];
    const float bB = b_ih[c1] + b_hh[c1];

    const size_t PSTRIDE = (size_t)BB * 4 * 256;     // u64s per parity
    unsigned long long* const base = pg + (size_t)b * 4 * 256;
    unsigned long long* const cp   = base + 64 * q + lane;   // + wg*256 (+par)
    unsigned long long* const pub  = base + (size_t)q * 256 + 64 * wv + lane;

    __syncthreads();   // xrow visible — the only barrier in the kernel

#pragma unroll 1
    for (int s = 1; s <= TT; ++s) {
        const int par = s & 1;
        const size_t po = (size_t)par * PSTRIDE;
        float zA, zB;
        if (s > 1) {
            // ---- pipelined poll: 3 rounds of 4 loads in flight ----
            unsigned long long* const p0 = cp + po + 0 * 256;
            unsigned long long* const p1 = cp + po + 1 * 256;
            unsigned long long* const p2 = cp + po + 2 * 256;
            unsigned long long* const p3 = cp + po + 3 * 256;
            const unsigned tg = (unsigned)s;
            unsigned long long v0, v1, v2, v3;
            unsigned long long A0, A1, A2, A3, B0, B1, B2, B3, C0, C1, C2, C3;
#define OKT(W0, W1, W2, W3) (((unsigned)((W0) >> 32) == tg) & \
                             ((unsigned)((W1) >> 32) == tg) & \
                             ((unsigned)((W2) >> 32) == tg) & \
                             ((unsigned)((W3) >> 32) == tg))
            A0 = ald(p0); A1 = ald(p1); A2 = ald(p2); A3 = ald(p3);
            B0 = ald(p0); B1 = ald(p1); B2 = ald(p2); B3 = ald(p3);
            __builtin_amdgcn_sched_barrier(0);
            for (;;) {
                C0 = ald(p0); C1 = ald(p1); C2 = ald(p2); C3 = ald(p3);
                __builtin_amdgcn_sched_barrier(0);
                if (OKT(A0, A1, A2, A3)) { v0 = A0; v1 = A1; v2 = A2; v3 = A3; break; }
                A0 = ald(p0); A1 = ald(p1); A2 = ald(p2); A3 = ald(p3);
                __builtin_amdgcn_sched_barrier(0);
                if (OKT(B0, B1, B2, B3)) { v0 = B0; v1 = B1; v2 = B2; v3 = B3; break; }
                B0 = ald(p0); B1 = ald(p1); B2 = ald(p2); B3 = ald(p3);
                __builtin_amdgcn_sched_barrier(0);
                if (OKT(C0, C1, C2, C3)) { v0 = C0; v1 = C1; v2 = C2; v3 = C3; break; }
            }
#undef OKT
            zA = (lo_f(v0) + lo_f(v1)) + (lo_f(v2) + lo_f(v3));
            zB = (hi_f(v0) + hi_f(v1)) + (hi_f(v2) + hi_f(v3));
        } else {
            zA = 0.f; zB = 0.f;   // h_0 = 0
        }
        const float xt = xrow[s - 1];
        const float hA = fast_tanh(fmaf(xt, wihA, zA + bA));
        const float hB = fast_tanh(fmaf(xt, wihB, zB + bB));
        stage[wv][par][lane] = pack_h2(hA, hB);      // same-wave DS, in-order

        if (s == TT) {
            if (wv == 0) {                            // final state out
                out[64 + b * HH + c0] = hA;
                out[64 + b * HH + c1] = hB;
            }
        } else {
            // ---- 128 dot2 over this WG's k-slice; publish partials tag s+1 --
            const uint4v* hp = reinterpret_cast<const uint4v*>(&stage[wv][par][0]);
            float a0 = 0.f, a1 = 0.f, a2 = 0.f, a3 = 0.f;
#pragma unroll
            for (int c = 0; c < 8; ++c) {
                const uint4v u = hp[c];
                a0 = dot2f(u[0], wh0[4*c+0], a0); a1 = dot2f(u[0], wh1[4*c+0], a1);
                a0 = dot2f(u[1], wh0[4*c+1], a0); a1 = dot2f(u[1], wh1[4*c+1], a1);
                a0 = dot2f(u[2], wh0[4*c+2], a0); a1 = dot2f(u[2], wh1[4*c+2], a1);
                a0 = dot2f(u[3], wh0[4*c+3], a0); a1 = dot2f(u[3], wh1[4*c+3], a1);
            }
#pragma unroll
            for (int c = 8; c < 16; ++c) {
                const uint4v u = hp[c];
                a2 = dot2f(u[0], wh0[4*c+0], a2); a3 = dot2f(u[0], wh1[4*c+0], a3);
                a2 = dot2f(u[1], wh0[4*c+1], a2); a3 = dot2f(u[1], wh1[4*c+1], a3);
                a2 = dot2f(u[2], wh0[4*c+2], a2); a3 = dot2f(u[2], wh1[4*c+2], a3);
                a2 = dot2f(u[3], wh0[4*c+3], a2); a3 = dot2f(u[3], wh1[4*c+3], a3);
            }
            const float pA = a0 + a2, pB = a1 + a3;
            const unsigned long long val =
                ((unsigned long long)(unsigned)(s + 1) << 32) | pack_h2(pA, pB);
            __hip_atomic_store(pub + (size_t)((s + 1) & 1) * PSTRIDE, val,
                               __ATOMIC_RELAXED, AG);
        }
    }

    // ---- epilogue: WG q==0 wave 0 rebuilds h_T from tag-TT partials ----
    if (q == 0 && wv == 0) {
        const size_t po = (size_t)(TT & 1) * PSTRIDE;
        float sacc = 0.f;
        const float xt = xrow[TT - 1];
#pragma unroll
        for (int pp = 0; pp < 4; ++pp) {
            const int P = 64 * pp + lane;     // pair -> rows 2P, 2P+1
            unsigned long long v0, v1, v2, v3;
            const unsigned tg = (unsigned)TT;
            for (;;) {
                v0 = ald(base + po + 0 * 256 + P);
                v1 = ald(base + po + 1 * 256 + P);
                v2 = ald(base + po + 2 * 256 + P);
                v3 = ald(base + po + 3 * 256 + P);
                const bool ok = ((unsigned)(v0 >> 32) == tg) &
                                ((unsigned)(v1 >> 32) == tg) &
                                ((unsigned)(v2 >> 32) == tg) &
                                ((unsigned)(v3 >> 32) == tg);
                if (ok) break;
            }
            const int rA = 2 * P, rB = rA + 1;
            const float zA = (lo_f(v0) + lo_f(v1)) + (lo_f(v2) + lo_f(v3));
            const float zB = (hi_f(v0) + hi_f(v1)) + (hi_f(v2) + hi_f(v3));
            const float hA = fast_tanh(fmaf(xt, W_ih[rA], zA + b_ih[rA] + b_hh[rA]));
            const float hB = fast_tanh(fmaf(xt, W_ih[rB], zB + b_ih[rB] + b_hh[rB]));
            sacc = fmaf(hA, W_out[rA], sacc);
            sacc = fmaf(hB, W_out[rB], sacc);
        }
#pragma unroll
        for (int off = 32; off; off >>= 1) sacc += __shfl_down(sacc, off, 64);
        if (lane == 0) out[b] = sacc + b_out[0];
    }
}

extern "C" void kernel_launch(void* const* d_in, const int* in_sizes, int n_in,
                              void* d_out, int out_size, void* d_ws, size_t ws_size,
                              hipStream_t stream) {
    const float* x     = (const float*)d_in[0];  // inputs [B,T,1]
    // d_in[1] = state (ignored; reference uses zero initial hidden state)
    const float* W_ih  = (const float*)d_in[2];
    const float* W_hh  = (const float*)d_in[3];
    const float* b_ih  = (const float*)d_in[4];
    const float* b_hh  = (const float*)d_in[5];
    const float* W_out = (const float*)d_in[6];
    const float* b_out = (const float*)d_in[7];

    unsigned long long* pg = (unsigned long long*)d_ws;  // [2][64][4][256] = 1MB

    // zero tags every call (ws is not re-poisoned between timed replays)
    hipMemsetAsync(pg, 0, 2ull * BB * 4 * 256 * 8, stream);

    rnn_part2<<<dim3(BB * 4), dim3(256), 0, stream>>>(
        x, W_ih, W_hh, b_ih, b_hh, W_out, b_out, (float*)d_out, pg);
}